// Round 2
// baseline (99.757 us; speedup 1.0000x reference)
//
#include <hip/hip_runtime.h>
#include <hip/hip_bf16.h>

#define NB 8192   // batch
#define ND 512    // feature dim
#define NC 512    // num classes
#define MARGIN_F 1.0f
#define BIGF 3.0e38f
#define BM 32     // rows per k2f block
#define NBLK 256  // NB / BM
#define NTHR 512  // 8 waves

typedef __attribute__((ext_vector_type(8))) short bf16x8;
typedef __attribute__((ext_vector_type(8))) unsigned short u16x8;
typedef __attribute__((ext_vector_type(4))) float f32x4;

__device__ __forceinline__ unsigned fkey(float f) {
    unsigned u = __float_as_uint(f);
    unsigned mask = (u & 0x80000000u) ? 0xFFFFFFFFu : 0x80000000u;
    return u ^ mask;
}
__device__ __forceinline__ float finv(unsigned k) {
    unsigned mask = (k & 0x80000000u) ? 0x80000000u : 0xFFFFFFFFu;
    return __uint_as_float(k ^ mask);
}
__device__ __forceinline__ unsigned short f2bf(float f) {
    __hip_bfloat16 h = __float2bfloat16(f);
    return __builtin_bit_cast(unsigned short, h);
}

#define GLOAD_LDS16(g, l)                                                    \
    __builtin_amdgcn_global_load_lds(                                        \
        (const __attribute__((address_space(1))) void*)(g),                  \
        (__attribute__((address_space(3))) void*)(l), 16, 0, 0)

// -------------------------------------------------------------------------
// k0c: centers-only prep. blocks 0..127: convert 4 center rows each
// (fp32->bf16) + csq. block 128: class histogram + zero accumulators.
// ~1.5 MB of traffic total.
// -------------------------------------------------------------------------
__global__ __launch_bounds__(256) void k0c(
    const float* __restrict__ centers, const int* __restrict__ targets,
    unsigned short* __restrict__ cenB, float* __restrict__ csq,
    unsigned* __restrict__ counts, unsigned long long* __restrict__ accums)
{
    const int bid = blockIdx.x;
    const int tid = threadIdx.x;

    if (bid == 128) {   // histogram block
        __shared__ unsigned hist[NC];
        if (tid < 3) accums[tid] = 0ull;   // accL, accP, ctr
        for (int i = tid; i < NC; i += 256) hist[i] = 0u;
        __syncthreads();
        for (int i = tid; i < NB; i += 256) atomicAdd(&hist[targets[i]], 1u);
        __syncthreads();
        for (int i = tid; i < NC; i += 256) counts[i] = hist[i];
        return;
    }

    const int wave = tid >> 6, lane = tid & 63;
    const int row = bid * 4 + wave;
    const float* src = centers + (size_t)row * ND;
    unsigned short* dst = cenB + (size_t)row * ND;

    float4 v1 = ((const float4*)src)[lane];
    float4 v2 = ((const float4*)src)[lane + 64];
    float s = v1.x*v1.x + v1.y*v1.y + v1.z*v1.z + v1.w*v1.w
            + v2.x*v2.x + v2.y*v2.y + v2.z*v2.z + v2.w*v2.w;

    ushort4 o1, o2;
    o1.x = f2bf(v1.x); o1.y = f2bf(v1.y); o1.z = f2bf(v1.z); o1.w = f2bf(v1.w);
    o2.x = f2bf(v2.x); o2.y = f2bf(v2.y); o2.z = f2bf(v2.z); o2.w = f2bf(v2.w);
    ((ushort4*)dst)[lane]      = o1;
    ((ushort4*)dst)[lane + 64] = o2;

    #pragma unroll
    for (int off = 32; off > 0; off >>= 1) s += __shfl_down(s, off);
    if (lane == 0) csq[row] = s;
}

// -------------------------------------------------------------------------
// k2f: fused convert + GEMM + epilogue + final reduce.
// 256 blocks x 512 thr (8 waves). Block owns rows [bid*32, bid*32+32),
// ALL 512 classes (BN=512) -> complete an/ap per row in-block, no partmin,
// no k3. A converted fp32->bf16 into LDS once (XOR-swizzled, T2).
// B (cenB, L2-resident) streamed per K-step via global_load_lds with a
// pre-swizzled SOURCE permutation (linear LDS dest, rule #21) so the
// ds_read_b128 fragment reads are 2-way (free) instead of 8-way.
// Loss/prec: fixed-point atomicAdd + last-block-writes-out (round-1 proven).
// -------------------------------------------------------------------------
__global__ __launch_bounds__(NTHR) void k2f(
    const float* __restrict__ inputs, const int* __restrict__ targets,
    const unsigned short* __restrict__ cenB, const unsigned* __restrict__ counts,
    const float* __restrict__ csq, unsigned long long* __restrict__ acc3,
    float* __restrict__ out)
{
    __shared__ __align__(16) unsigned short As[BM * ND];      // 32 KB, XOR-swizzled
    __shared__ __align__(16) unsigned short Bs[2][NC * 32];   // 2 x 32 KB, perm slots
    __shared__ float    csqL[NC];
    __shared__ float    rsqL[BM];
    __shared__ float    apL[BM];
    __shared__ int      tgtL[BM];
    __shared__ unsigned anL[BM];

    const int tid  = threadIdx.x;
    const int w    = tid >> 6;
    const int lane = tid & 63;
    const int qd   = lane >> 4;   // k-chunk 0..3
    const int ln   = lane & 15;
    const int rbase = blockIdx.x * BM;

    // ---- B staging source precompute (4 issues/wave/K-step) --------------
    // Slot s = w*256 + t*64 + lane holds logical (c, q):
    //   rslot = s>>2, qs = s&3
    //   c = (rslot & ~7) | rotr1_3(rslot&7);  q = qs ^ (c&3)
    // Reader inverts with rotl1_3 -> 8 distinct banksets over 8 lanes.
    const unsigned short* gBsrc[4];
    #pragma unroll
    for (int t = 0; t < 4; ++t) {
        const int s     = w * 256 + t * 64 + lane;
        const int rslot = s >> 2, qs = s & 3;
        const int c     = (rslot & ~7) | (((rslot >> 1) & 3) | ((rslot & 1) << 2));
        const int ql    = qs ^ (c & 3);
        gBsrc[t] = cenB + (size_t)c * ND + ql * 8;
    }

#define STAGE_B(buf, kb) do {                                                \
        _Pragma("unroll")                                                    \
        for (int t = 0; t < 4; ++t)                                          \
            GLOAD_LDS16(gBsrc[t] + (kb), &Bs[buf][(w * 256 + t * 64) * 8]);  \
    } while (0)

    // issue first B tile (kb=0) now; its latency hides under A conversion
    STAGE_B(0, 0);

    // ---- prologue: A fp32->bf16 into swizzled LDS + rsq ------------------
    {
        const int row = tid >> 4;          // 0..31
        const int seg = tid & 15;          // 32 elements each
        const float* asrc = inputs + (size_t)(rbase + row) * ND + seg * 32;
        float ss = 0.0f;
        #pragma unroll
        for (int k = 0; k < 4; ++k) {
            float4 u = ((const float4*)asrc)[k * 2];
            float4 v = ((const float4*)asrc)[k * 2 + 1];
            ss += u.x*u.x + u.y*u.y + u.z*u.z + u.w*u.w
                + v.x*v.x + v.y*v.y + v.z*v.z + v.w*v.w;
            u16x8 pk;
            pk[0] = f2bf(u.x); pk[1] = f2bf(u.y); pk[2] = f2bf(u.z); pk[3] = f2bf(u.w);
            pk[4] = f2bf(v.x); pk[5] = f2bf(v.y); pk[6] = f2bf(v.z); pk[7] = f2bf(v.w);
            int byte = row * 1024 + (seg * 32 + k * 8) * 2;
            byte ^= (row & 7) << 4;                       // T2 XOR swizzle
            *(u16x8*)((char*)As + byte) = pk;
        }
        ss += __shfl_down(ss, 8); ss += __shfl_down(ss, 4);
        ss += __shfl_down(ss, 2); ss += __shfl_down(ss, 1);
        if (seg == 0) rsqL[row] = ss;
    }
    csqL[tid] = (counts[tid] > 0u) ? csq[tid] : BIGF;     // NTHR == NC
    if (tid < BM) { tgtL[tid] = targets[rbase + tid]; anL[tid] = 0xFFFFFFFFu; }
    __syncthreads();   // A in LDS, B tile 0 landed (barrier drains vmcnt)

    // ---- fragment address precompute (k-invariant) -----------------------
    int boff[4];
    #pragma unroll
    for (int j = 0; j < 4; ++j) {
        const int c     = w * 64 + j * 16 + ln;
        const int rslot = (c & ~7) | (((c << 1) & 6) | ((c >> 2) & 1));
        boff[j] = rslot * 64 + ((qd ^ (c & 3)) * 16);
    }

    // ---- K-loop: 16 steps, 2-phase double-buffered B ---------------------
    f32x4 acc[2][4] = {};
    int cur = 0;
    #pragma unroll
    for (int kb = 0; kb < ND; kb += 32) {
        if (kb + 32 < ND) STAGE_B(cur ^ 1, kb + 32);
        bf16x8 a[2], b[4];
        #pragma unroll
        for (int i = 0; i < 2; ++i) {
            int byte = ((i * 16 + ln) * 1024 + kb * 2 + qd * 16) ^ ((ln & 7) << 4);
            a[i] = *(const bf16x8*)((const char*)As + byte);
        }
        #pragma unroll
        for (int j = 0; j < 4; ++j)
            b[j] = *(const bf16x8*)((const char*)&Bs[cur][0] + boff[j]);
        #pragma unroll
        for (int i = 0; i < 2; ++i)
            #pragma unroll
            for (int j = 0; j < 4; ++j)
                acc[i][j] = __builtin_amdgcn_mfma_f32_16x16x32_bf16(a[i], b[j], acc[i][j], 0, 0, 0);
        __syncthreads();
        cur ^= 1;
    }

    // ---- epilogue: per-row min over non-target classes + ap --------------
    // C/D layout: col = ln, row = qd*4 + r (within 16x16 frag).
    #pragma unroll
    for (int i = 0; i < 2; ++i) {
        #pragma unroll
        for (int r = 0; r < 4; ++r) {
            const int rlocal = i * 16 + qd * 4 + r;
            const int tr     = tgtL[rlocal];
            float m = BIGF;
            #pragma unroll
            for (int j = 0; j < 4; ++j) {
                const int c = w * 64 + j * 16 + ln;
                const float val = csqL[c] - 2.0f * acc[i][j][r];
                if (c == tr) {
                    apL[rlocal] = val;     // exactly one lane in the grid-row
                } else {
                    m = fminf(m, val);
                }
            }
            #pragma unroll
            for (int off = 1; off < 16; off <<= 1)
                m = fminf(m, __shfl_xor(m, off));
            if (ln == 0) atomicMin(&anL[rlocal], fkey(m));
        }
    }
    __syncthreads();

    // ---- final: loss/prec for this block's 32 rows + global reduce -------
    if (tid < 64) {
        double a = 0.0, p = 0.0;
        if (tid < BM) {
            const float mv = finv(anL[tid]);
            const float s  = rsqL[tid];
            const float an = sqrtf(fmaxf(s + mv,        1e-12f));
            const float ap = sqrtf(fmaxf(s + apL[tid],  1e-12f));
            a = (double)fmaxf(0.0f, ap - an + MARGIN_F);
            p = (an > ap) ? 1.0 : 0.0;
        }
        #pragma unroll
        for (int off = 32; off > 0; off >>= 1) {
            a += __shfl_down(a, off);
            p += __shfl_down(p, off);
        }
        if (tid == 0) {
            atomicAdd(&acc3[0], (unsigned long long)(a * 4294967296.0 + 0.5));
            atomicAdd(&acc3[1], (unsigned long long)(p + 0.5));
            __threadfence();
            unsigned* ctr = (unsigned*)&acc3[2];
            if (atomicAdd(ctr, 1u) == NBLK - 1) {
                unsigned long long ls = atomicAdd(&acc3[0], 0ull);
                unsigned long long ps = atomicAdd(&acc3[1], 0ull);
                out[0] = (float)((double)ls / (4294967296.0 * (double)NB));
                out[1] = (float)((double)ps / (double)NB);
            }
        }
    }
}

extern "C" void kernel_launch(void* const* d_in, const int* in_sizes, int n_in,
                              void* d_out, int out_size, void* d_ws, size_t ws_size,
                              hipStream_t stream) {
    const float* inputs  = (const float*)d_in[0];
    const int*   targets = (const int*)d_in[1];
    const float* centers = (const float*)d_in[2];
    float* out = (float*)d_out;

    // ws layout (bytes):
    char* wp = (char*)d_ws;
    unsigned short* cenB   = (unsigned short*)(wp);            // 512*512*2 = 524288
    float*          csqv   = (float*)(wp + 524288);            // 512*4
    unsigned*       counts = (unsigned*)(wp + 526336);         // 512*4
    unsigned long long* accums = (unsigned long long*)(wp + 528384); // 24 B

    k0c<<<129, 256, 0, stream>>>(centers, targets, cenB, csqv, counts, accums);
    k2f<<<NBLK, NTHR, 0, stream>>>(inputs, targets, cenB, counts, csqv,
                                   accums, out);
}